// Round 5
// baseline (4387.485 us; speedup 1.0000x reference)
//
#include <hip/hip_runtime.h>

// ---------------------------------------------------------------------------
// DVGMamba forward. Round 5: launch-count reduction.
//  - single-pass chained selective scan (agent-scope atomics, per-layer flags)
//  - fused conv+silu+xproj+dt
//  - fused GLU inside fc2 GEMM A-staging
//  - two-stage patch mean
// b=2, l=64, S=256 tokens, D=512, DIN=1024, DS=16, DTR=32, K=4, Layers=8
// ---------------------------------------------------------------------------

#define NTOK 512
#define SEQ  256
#define CS   32     // scan chunk size
#define NC   8      // chunks

typedef __attribute__((ext_vector_type(8))) short bf16x8;
typedef __attribute__((ext_vector_type(16))) float f32x16;
typedef unsigned long long u64;

__device__ __forceinline__ float silu_f(float x) { return x / (1.0f + expf(-x)); }
__device__ __forceinline__ float softplus_f(float x) {
  return (x > 20.0f) ? x : log1pf(expf(x));
}

// split fp32 -> (hi bf16, lo bf16) by truncation; packed 2x bf16 per dword
__device__ __forceinline__ void split_pack(float4 v, uint2* hi, uint2* lo) {
  uint ux = __float_as_uint(v.x), uy = __float_as_uint(v.y);
  uint uz = __float_as_uint(v.z), uw = __float_as_uint(v.w);
  hi->x = (ux >> 16) | (uy & 0xffff0000u);
  hi->y = (uz >> 16) | (uw & 0xffff0000u);
  float lx = v.x - __uint_as_float(ux & 0xffff0000u);
  float ly = v.y - __uint_as_float(uy & 0xffff0000u);
  float lz = v.z - __uint_as_float(uz & 0xffff0000u);
  float lw = v.w - __uint_as_float(uw & 0xffff0000u);
  lo->x = (__float_as_uint(lx) >> 16) | (__float_as_uint(ly) & 0xffff0000u);
  lo->y = (__float_as_uint(lz) >> 16) | (__float_as_uint(lw) & 0xffff0000u);
}

// --------------------------- split-bf16 MFMA NT GEMM -----------------------
// C[M,N] (partials over grid.z) = A[M,K] @ B[N,K]^T, 64x64 tile, 4 waves.
__global__ __launch_bounds__(256) void gemm_bs_k(const float* __restrict__ A,
                                                 const float* __restrict__ B,
                                                 float* __restrict__ C,
                                                 int M, int N, int K, int Kc) {
  __shared__ alignas(16) ushort sAh[2][2][512];
  __shared__ alignas(16) ushort sAl[2][2][512];
  __shared__ alignas(16) ushort sBh[2][2][512];
  __shared__ alignas(16) ushort sBl[2][2][512];
  int t = threadIdx.x;
  int bn = blockIdx.x, bm = blockIdx.y, z = blockIdx.z;
  const float* Ab = A + (size_t)bm * 64 * K + (size_t)z * Kc;
  const float* Bb = B + (size_t)bn * 64 * K + (size_t)z * Kc;
  float* Cb = C + (size_t)z * M * N;
  int r = t >> 2, kc = (t & 3) << 2;
  int st = r >> 5, m = r & 31;
  int off = ((kc >> 3) << 8) + (m << 3) + (kc & 7);
  int w = t >> 6, lane = t & 63;
  int wr = w >> 1, wc = w & 1;

  f32x16 acc;
#pragma unroll
  for (int i = 0; i < 16; ++i) acc[i] = 0.f;

  int nk = Kc >> 4;
  float4 a4 = *(const float4*)&Ab[(size_t)r * K + kc];
  float4 b4 = *(const float4*)&Bb[(size_t)r * K + kc];
  {
    uint2 hi, lo;
    split_pack(a4, &hi, &lo);
    *(uint2*)&sAh[0][st][off] = hi; *(uint2*)&sAl[0][st][off] = lo;
    split_pack(b4, &hi, &lo);
    *(uint2*)&sBh[0][st][off] = hi; *(uint2*)&sBl[0][st][off] = lo;
  }
  __syncthreads();
  for (int ks = 0; ks < nk; ++ks) {
    int buf = ks & 1;
    if (ks + 1 < nk) {
      a4 = *(const float4*)&Ab[(size_t)r * K + (ks + 1) * 16 + kc];
      b4 = *(const float4*)&Bb[(size_t)r * K + (ks + 1) * 16 + kc];
    }
    bf16x8 ah = *(bf16x8*)&sAh[buf][wr][lane << 3];
    bf16x8 al = *(bf16x8*)&sAl[buf][wr][lane << 3];
    bf16x8 bh = *(bf16x8*)&sBh[buf][wc][lane << 3];
    bf16x8 bl = *(bf16x8*)&sBl[buf][wc][lane << 3];
    acc = __builtin_amdgcn_mfma_f32_32x32x16_bf16(ah, bh, acc, 0, 0, 0);
    acc = __builtin_amdgcn_mfma_f32_32x32x16_bf16(al, bh, acc, 0, 0, 0);
    acc = __builtin_amdgcn_mfma_f32_32x32x16_bf16(ah, bl, acc, 0, 0, 0);
    if (ks + 1 < nk) {
      uint2 hi, lo;
      split_pack(a4, &hi, &lo);
      *(uint2*)&sAh[buf ^ 1][st][off] = hi; *(uint2*)&sAl[buf ^ 1][st][off] = lo;
      split_pack(b4, &hi, &lo);
      *(uint2*)&sBh[buf ^ 1][st][off] = hi; *(uint2*)&sBl[buf ^ 1][st][off] = lo;
    }
    __syncthreads();
  }
  int col = lane & 31, rq = lane >> 5;
  float* Cw = Cb + (size_t)(bm * 64 + wr * 32) * N + bn * 64 + wc * 32 + col;
#pragma unroll
  for (int rg = 0; rg < 16; ++rg) {
    int row = (rg & 3) + ((rg >> 2) << 3) + (rq << 2);
    Cw[(size_t)row * N] = acc[rg];
  }
}

// --------------------------- GEMM with fused GLU on A ----------------------
// A_logical[r,k] = g[r*2048+k] * silu(g[r*2048+1024+k]); K = 1024.
__global__ __launch_bounds__(256) void gemm_glu_k(const float* __restrict__ G,
                                                  const float* __restrict__ B,
                                                  float* __restrict__ C,
                                                  int M, int N, int K, int Kc) {
  __shared__ alignas(16) ushort sAh[2][2][512];
  __shared__ alignas(16) ushort sAl[2][2][512];
  __shared__ alignas(16) ushort sBh[2][2][512];
  __shared__ alignas(16) ushort sBl[2][2][512];
  int t = threadIdx.x;
  int bn = blockIdx.x, bm = blockIdx.y, z = blockIdx.z;
  const float* Gb = G + (size_t)bm * 64 * 2048 + (size_t)z * Kc;
  const float* Bb = B + (size_t)bn * 64 * K + (size_t)z * Kc;
  float* Cb = C + (size_t)z * M * N;
  int r = t >> 2, kc = (t & 3) << 2;
  int st = r >> 5, m = r & 31;
  int off = ((kc >> 3) << 8) + (m << 3) + (kc & 7);
  int w = t >> 6, lane = t & 63;
  int wr = w >> 1, wc = w & 1;

  f32x16 acc;
#pragma unroll
  for (int i = 0; i < 16; ++i) acc[i] = 0.f;

  int nk = Kc >> 4;
  const float* gr = Gb + (size_t)r * 2048 + kc;
  float4 ga = *(const float4*)&gr[0];
  float4 gz = *(const float4*)&gr[1024];
  float4 b4 = *(const float4*)&Bb[(size_t)r * K + kc];
  {
    float4 a4 = {ga.x * silu_f(gz.x), ga.y * silu_f(gz.y),
                 ga.z * silu_f(gz.z), ga.w * silu_f(gz.w)};
    uint2 hi, lo;
    split_pack(a4, &hi, &lo);
    *(uint2*)&sAh[0][st][off] = hi; *(uint2*)&sAl[0][st][off] = lo;
    split_pack(b4, &hi, &lo);
    *(uint2*)&sBh[0][st][off] = hi; *(uint2*)&sBl[0][st][off] = lo;
  }
  __syncthreads();
  for (int ks = 0; ks < nk; ++ks) {
    int buf = ks & 1;
    if (ks + 1 < nk) {
      ga = *(const float4*)&gr[(ks + 1) * 16];
      gz = *(const float4*)&gr[1024 + (ks + 1) * 16];
      b4 = *(const float4*)&Bb[(size_t)r * K + (ks + 1) * 16 + kc];
    }
    bf16x8 ah = *(bf16x8*)&sAh[buf][wr][lane << 3];
    bf16x8 al = *(bf16x8*)&sAl[buf][wr][lane << 3];
    bf16x8 bh = *(bf16x8*)&sBh[buf][wc][lane << 3];
    bf16x8 bl = *(bf16x8*)&sBl[buf][wc][lane << 3];
    acc = __builtin_amdgcn_mfma_f32_32x32x16_bf16(ah, bh, acc, 0, 0, 0);
    acc = __builtin_amdgcn_mfma_f32_32x32x16_bf16(al, bh, acc, 0, 0, 0);
    acc = __builtin_amdgcn_mfma_f32_32x32x16_bf16(ah, bl, acc, 0, 0, 0);
    if (ks + 1 < nk) {
      float4 a4 = {ga.x * silu_f(gz.x), ga.y * silu_f(gz.y),
                   ga.z * silu_f(gz.z), ga.w * silu_f(gz.w)};
      uint2 hi, lo;
      split_pack(a4, &hi, &lo);
      *(uint2*)&sAh[buf ^ 1][st][off] = hi; *(uint2*)&sAl[buf ^ 1][st][off] = lo;
      split_pack(b4, &hi, &lo);
      *(uint2*)&sBh[buf ^ 1][st][off] = hi; *(uint2*)&sBl[buf ^ 1][st][off] = lo;
    }
    __syncthreads();
  }
  int col = lane & 31, rq = lane >> 5;
  float* Cw = Cb + (size_t)(bm * 64 + wr * 32) * N + bn * 64 + wc * 32 + col;
#pragma unroll
  for (int rg = 0; rg < 16; ++rg) {
    int row = (rg & 3) + ((rg >> 2) << 3) + (rq << 2);
    Cw[(size_t)row * N] = acc[rg];
  }
}

// --------------------------- patch mean, two stage -------------------------
// stage 1: 1792 blocks (bl*14+hb), 192 thr own (c,hi,wi4); sum over wb.
__global__ void patch_part_k(const float* __restrict__ img, float* __restrict__ pmp) {
  int blk = blockIdx.x;
  int bl = blk / 14, hb = blk % 14;
  int t = threadIdx.x;                 // = c*64 + hi*4 + wi4
  int c = t >> 6, hi = (t >> 2) & 15, wi4 = t & 3;
  const float* base = img + (size_t)bl * 3 * 50176 + (size_t)c * 50176 +
                      (size_t)(hb * 16 + hi) * 224 + wi4 * 4;
  float4 s = {0.f, 0.f, 0.f, 0.f};
#pragma unroll
  for (int wb = 0; wb < 14; ++wb) {
    float4 v = *(const float4*)&base[wb * 16];
    s.x += v.x; s.y += v.y; s.z += v.z; s.w += v.w;
  }
  ((float4*)(pmp + (size_t)blk * 768))[t] = s;
}

// stage 2: 128 blocks, 192 thr: reduce 14 partials, scale by 1/196.
__global__ void patch_red_k(const float* __restrict__ pmp, float* __restrict__ meanp) {
  int bl = blockIdx.x;
  int t = threadIdx.x;
  float4 s = {0.f, 0.f, 0.f, 0.f};
  for (int hb = 0; hb < 14; ++hb) {
    float4 v = ((const float4*)(pmp + (size_t)(bl * 14 + hb) * 768))[t];
    s.x += v.x; s.y += v.y; s.z += v.z; s.w += v.w;
  }
  const float inv = 1.0f / 196.0f;
  float4 o = {s.x * inv, s.y * inv, s.z * inv, s.w * inv};
  ((float4*)(meanp + (size_t)bl * 768))[t] = o;
}

// --------------------------- tokenize (scatter) ----------------------------
__global__ void tokenize_k(const float* __restrict__ imgp,
                           const float* __restrict__ states,
                           const float* __restrict__ actions,
                           const float* __restrict__ pb,
                           const float* __restrict__ sw, const float* __restrict__ sb,
                           const float* __restrict__ aw, const float* __restrict__ ab,
                           float* __restrict__ hidden, float* __restrict__ residual) {
  int tok = blockIdx.x;
  int t = threadIdx.x;
  int j = tok & 3;
  int bl = tok >> 2;
  int o0 = t * 4;
  float out[4];
  if (j == 0) {
    float4 a = ((const float4*)pb)[t];
    const float* ip = imgp + (size_t)bl * 512;
#pragma unroll
    for (int p = 0; p < 8; ++p) {
      float4 v = ((const float4*)(ip + (size_t)p * 65536))[t];
      a.x += v.x; a.y += v.y; a.z += v.z; a.w += v.w;
    }
    out[0] = a.x; out[1] = a.y; out[2] = a.z; out[3] = a.w;
  } else if (j == 1) {
    const float* sv = states + (size_t)bl * 21;
#pragma unroll
    for (int i = 0; i < 4; ++i) {
      int o = o0 + i;
      float acc = sb[o];
      for (int k = 0; k < 7; ++k) acc += sw[o * 7 + k] * sv[k];
      out[i] = acc;
    }
  } else {
    const float* av = actions + ((size_t)bl * 3 + (j - 2)) * 4;
#pragma unroll
    for (int i = 0; i < 4; ++i) {
      int o = o0 + i;
      float acc = ab[o];
      for (int k = 0; k < 4; ++k) acc += aw[o * 4 + k] * av[k];
      out[i] = acc;
    }
  }
  float4 ov = {out[0], out[1], out[2], out[3]};
  ((float4*)(hidden + (size_t)tok * 512))[t] = ov;
  float4 z4 = {0.f, 0.f, 0.f, 0.f};
  ((float4*)(residual + (size_t)tok * 512))[t] = z4;
}

// --------------------------- add + rmsnorm ---------------------------------
__global__ void addnorm_k(const float* __restrict__ hid, int parts,
                          float* __restrict__ res,
                          const float* __restrict__ w, float* __restrict__ xn) {
  int tok = blockIdx.x;
  int t = threadIdx.x;
  float4* r4 = (float4*)(res + (size_t)tok * 512);
  float4 r = r4[t];
  const float4* hp = (const float4*)(hid + (size_t)tok * 512);
  for (int p = 0; p < parts; ++p) {
    float4 h = hp[t];
    r.x += h.x; r.y += h.y; r.z += h.z; r.w += h.w;
    hp += 65536;                       // 512*512 floats between parts
  }
  r4[t] = r;
  float ss = r.x * r.x + r.y * r.y + r.z * r.z + r.w * r.w;
  for (int off = 32; off; off >>= 1) ss += __shfl_down(ss, off, 64);
  __shared__ float s2[2];
  if ((t & 63) == 0) s2[t >> 6] = ss;
  __syncthreads();
  float tot = s2[0] + s2[1];
  float scale = rsqrtf(tot * (1.0f / 512.0f) + 1e-5f);
  float4 wv = ((const float4*)w)[t];
  float4 o = {r.x * scale * wv.x, r.y * scale * wv.y,
              r.z * scale * wv.z, r.w * scale * wv.w};
  ((float4*)(xn + (size_t)tok * 512))[t] = o;
}

// --------------------------- fused conv+silu+xproj+dt ----------------------
// 512 blocks (token), 256 thr. conv over xz rows s-3..s, then per-token
// x_proj matvec + dt softplus, exactly as before but from LDS.
__global__ __launch_bounds__(256) void convproj_k(const float* __restrict__ xz,
                                                  const float* __restrict__ cw,
                                                  const float* __restrict__ cb,
                                                  const float* __restrict__ xpw,
                                                  const float* __restrict__ dtw,
                                                  const float* __restrict__ dtbias,
                                                  float* __restrict__ xc,
                                                  float* __restrict__ proj,
                                                  float* __restrict__ dt) {
  int tok = blockIdx.x;
  int t = threadIdx.x;
  int b = tok >> 8, s = tok & 255;
  __shared__ float xr[1024];
  __shared__ float pp[4][64];
  __shared__ float pr[64];
  int d4 = t * 4;
  float4 cw0 = ((const float4*)cw)[d4];
  float4 cw1 = ((const float4*)cw)[d4 + 1];
  float4 cw2 = ((const float4*)cw)[d4 + 2];
  float4 cw3 = ((const float4*)cw)[d4 + 3];
  float acc0 = cb[d4], acc1 = cb[d4 + 1], acc2 = cb[d4 + 2], acc3 = cb[d4 + 3];
  const float* base = xz + (size_t)b * 256 * 2048 + d4;
  const float wk0[4] = {cw0.x, cw0.y, cw0.z, cw0.w};
  const float wk1[4] = {cw1.x, cw1.y, cw1.z, cw1.w};
  const float wk2[4] = {cw2.x, cw2.y, cw2.z, cw2.w};
  const float wk3[4] = {cw3.x, cw3.y, cw3.z, cw3.w};
#pragma unroll
  for (int k = 0; k < 4; ++k) {
    int row = s + k - 3;
    if (row >= 0) {
      float4 v = *(const float4*)&base[(size_t)row * 2048];
      acc0 += wk0[k] * v.x; acc1 += wk1[k] * v.y;
      acc2 += wk2[k] * v.z; acc3 += wk3[k] * v.w;
    }
  }
  float4 xc4 = {silu_f(acc0), silu_f(acc1), silu_f(acc2), silu_f(acc3)};
  ((float4*)(xc + (size_t)tok * 1024))[t] = xc4;
  *(float4*)&xr[d4] = xc4;
  __syncthreads();
  int n = t & 63, q = t >> 6;
  {
    const float* wrow = xpw + (size_t)n * 1024 + q * 256;
    const float* xq = xr + q * 256;
    float acc = 0.f;
    for (int k = 0; k < 256; k += 4)
      acc += wrow[k] * xq[k] + wrow[k + 1] * xq[k + 1] +
             wrow[k + 2] * xq[k + 2] + wrow[k + 3] * xq[k + 3];
    pp[q][n] = acc;
  }
  __syncthreads();
  if (t < 64) {
    float v = pp[0][t] + pp[1][t] + pp[2][t] + pp[3][t];
    pr[t] = v;
    proj[(size_t)tok * 64 + t] = v;
  }
  __syncthreads();
#pragma unroll
  for (int i = 0; i < 4; ++i) {
    int d = t * 4 + i;
    const float* dw = dtw + (size_t)d * 32;
    float a = dtbias[d];
    for (int k = 0; k < 32; ++k) a += dw[k] * pr[k];
    dt[(size_t)tok * 1024 + d] = softplus_f(a);
  }
}

// --------------------------- single-pass chained scan ----------------------
// 2048 blocks: blk = g*8 + c (g = b*128+dgroup, c = chunk). 128 thr = 8d x 16n.
// Chunk c waits (agent-scope acquire) on chunk c-1's inclusive pair, then
// publishes its own and re-walks with gating. All blocks co-resident
// (2048 blocks x 2 waves = 4096 waves <= 8192 device capacity; 8 KB LDS).
__global__ __launch_bounds__(128) void scan_k(const float* __restrict__ dt,
                                              const float* __restrict__ proj,
                                              const float* __restrict__ xc,
                                              const float* __restrict__ xz,
                                              const float* __restrict__ alog,
                                              const float* __restrict__ Dp,
                                              u64* __restrict__ pairs,
                                              int* __restrict__ flags,
                                              float* __restrict__ yz) {
  __shared__ float sDt[CS][8];
  __shared__ float sXc[CS][8];
  __shared__ float sZ[CS][8];
  __shared__ float sBC[CS][32];
  __shared__ float sY[CS][8];
  int t = threadIdx.x;
  int blk = blockIdx.x;
  int g = blk >> 3, c = blk & 7;
  int b = g >> 7;
  int d0 = (g & 127) << 3;
  int dl = t >> 4, n = t & 15;
  int d = d0 + dl;
  int s0 = c * CS;
  float A = -expf(alog[d * 16 + n]);
  float dp = Dp[d];
  const float* dtb = dt + ((size_t)b * SEQ + s0) * 1024 + d0;
  const float* xcb = xc + ((size_t)b * SEQ + s0) * 1024 + d0;
  const float* zb  = xz + ((size_t)b * SEQ + s0) * 2048 + 1024 + d0;
  const float* pbp = proj + ((size_t)b * SEQ + s0) * 64 + 32;
  float* yb = yz + ((size_t)b * SEQ + s0) * 1024 + d0;
  // stage all tiles
  bool lowh = t < 64;
  int u = lowh ? t : t - 64;
  int li = u >> 1, lc4 = (u & 1) * 4;
  if (lowh) {
    *(float4*)&sDt[li][lc4] = *(const float4*)&dtb[(size_t)li * 1024 + lc4];
    *(float4*)&sXc[li][lc4] = *(const float4*)&xcb[(size_t)li * 1024 + lc4];
  } else {
    *(float4*)&sZ[li][lc4] = *(const float4*)&zb[(size_t)li * 2048 + lc4];
  }
  {
    int v0i = t >> 3, v0c = (t & 7) * 4;
    int v1i = (t + 128) >> 3, v1c = ((t + 128) & 7) * 4;
    *(float4*)&sBC[v0i][v0c] = *(const float4*)&pbp[(size_t)v0i * 64 + v0c];
    *(float4*)&sBC[v1i][v1c] = *(const float4*)&pbp[(size_t)v1i * 64 + v1c];
  }
  __syncthreads();
  // local chunk pair (Ap, Bl): h_out = Ap*h_in + Bl
  float Ap = 1.f, Bl = 0.f;
#pragma unroll
  for (int i = 0; i < CS; ++i) {
    float dtv = sDt[i][dl];
    float dA = __expf(dtv * A);
    Bl = dA * Bl + dtv * sBC[i][n] * sXc[i][dl];
    Ap *= dA;
  }
  // chain: get inclusive prefix of c-1
  float Aprev = 1.f, Bprev = 0.f;
  if (c > 0) {
    if (t == 0) {
      while (__hip_atomic_load(&flags[blk - 1], __ATOMIC_ACQUIRE,
                               __HIP_MEMORY_SCOPE_AGENT) != 1)
        __builtin_amdgcn_s_sleep(8);
    }
    __syncthreads();
    u64 pv = __hip_atomic_load(&pairs[(size_t)(blk - 1) * 128 + t],
                               __ATOMIC_RELAXED, __HIP_MEMORY_SCOPE_AGENT);
    float2 pf = *(float2*)&pv;
    Aprev = pf.x; Bprev = pf.y;
  }
  if (c < 7) {
    float2 inc = make_float2(Aprev * Ap, Ap * Bprev + Bl);
    u64 iv = *(u64*)&inc;
    __hip_atomic_store(&pairs[(size_t)blk * 128 + t], iv,
                       __ATOMIC_RELAXED, __HIP_MEMORY_SCOPE_AGENT);
    __syncthreads();
    if (t == 0) {
      __threadfence();
      __hip_atomic_store(&flags[blk], 1, __ATOMIC_RELEASE,
                         __HIP_MEMORY_SCOPE_AGENT);
    }
  }
  // re-walk with h0 = Bprev, gate, write
  float h = Bprev;
#pragma unroll
  for (int i = 0; i < CS; ++i) {
    float dtv = sDt[i][dl];
    float xcv = sXc[i][dl];
    float dA = __expf(dtv * A);
    h = dA * h + dtv * sBC[i][n] * xcv;
    float yc = h * sBC[i][16 + n];
    yc += __shfl_xor(yc, 1, 64);
    yc += __shfl_xor(yc, 2, 64);
    yc += __shfl_xor(yc, 4, 64);
    yc += __shfl_xor(yc, 8, 64);
    if (n == 0) sY[i][dl] = (yc + dp * xcv) * silu_f(sZ[i][dl]);
  }
  __syncthreads();
  if (lowh)
    *(float4*)&yb[(size_t)li * 1024 + lc4] = *(const float4*)&sY[li][lc4];
}

// --------------------------- head + |diff| ---------------------------------
__global__ void head_k(const float* __restrict__ hf, const float* __restrict__ hw,
                       const float* __restrict__ hb, const float* __restrict__ labels,
                       float* __restrict__ preds, float* __restrict__ labs) {
  int blk = blockIdx.x;
  int j = blk % 3;
  int l = (blk / 3) % 64;
  int b = blk / 192;
  int row = b * 256 + l * 4 + 1 + j;
  int t = threadIdx.x;
  const float* x = hf + (size_t)row * 512;
  float acc[4] = {0.f, 0.f, 0.f, 0.f};
  for (int k = t; k < 512; k += 64) {
    float xv = x[k];
#pragma unroll
    for (int a = 0; a < 4; ++a) acc[a] += xv * hw[a * 512 + k];
  }
  for (int off = 32; off; off >>= 1) {
#pragma unroll
    for (int a = 0; a < 4; ++a) acc[a] += __shfl_down(acc[a], off, 64);
  }
  if (t == 0) {
    const float* lab = labels + (size_t)blk * 4;
    float sd = 0.f;
#pragma unroll
    for (int a = 0; a < 4; ++a) {
      float p = acc[a] + hb[a];
      preds[(size_t)blk * 4 + a] = p;
      sd += fabsf(p - lab[a]);
    }
    labs[blk] = sd;
  }
}

// --------------------------- loss ------------------------------------------
__global__ void loss_k(const float* __restrict__ labs, const int* __restrict__ seqlen,
                       float* __restrict__ out) {
  int t = threadIdx.x;
  int b = t >> 6, l = t & 63;
  float la = (labs[(b * 64 + l) * 3] + labs[(b * 64 + l) * 3 + 1] +
              labs[(b * 64 + l) * 3 + 2]) * (1.0f / 12.0f);
  float m = (l < seqlen[b]) ? 1.f : 0.f;
  float v = la * m;
  for (int off = 32; off; off >>= 1) {
    v += __shfl_down(v, off, 64);
    m += __shfl_down(m, off, 64);
  }
  __shared__ float sb_[2];
  if ((t & 63) == 0) sb_[b] = v / fmaxf(m, 1.0f);
  __syncthreads();
  if (t == 0) out[0] = 0.5f * (sb_[0] + sb_[1]);
}

// ---------------------------------------------------------------------------
extern "C" void kernel_launch(void* const* d_in, const int* in_sizes, int n_in,
                              void* d_out, int out_size, void* d_ws, size_t ws_size,
                              hipStream_t stream) {
  const float* images     = (const float*)d_in[0];
  const int*   seq_length = (const int*)d_in[1];
  const float* states     = (const float*)d_in[2];
  const float* actions    = (const float*)d_in[3];
  const float* labels     = (const float*)d_in[4];
  const float* patch_w    = (const float*)d_in[5];
  const float* patch_b    = (const float*)d_in[6];
  const float* state_w    = (const float*)d_in[7];
  const float* state_b    = (const float*)d_in[8];
  const float* act_w      = (const float*)d_in[9];
  const float* act_b      = (const float*)d_in[10];
  const float* norm1_w    = (const float*)d_in[11];
  const float* in_proj_w  = (const float*)d_in[12];
  const float* conv_w     = (const float*)d_in[13];
  const float* conv_b     = (const float*)d_in[14];
  const float* x_proj_w   = (const float*)d_in[15];
  const float* dt_w       = (const float*)d_in[16];
  const float* dt_b       = (const float*)d_in[17];
  const float* A_log      = (const float*)d_in[18];
  const float* Dp         = (const float*)d_in[19];
  const float* out_proj_w = (const float*)d_in[20];
  const float* norm2_w    = (const float*)d_in[21];
  const float* fc1_w      = (const float*)d_in[22];
  const float* fc2_w      = (const float*)d_in[23];
  const float* norm_f_w   = (const float*)d_in[24];
  const float* head_w     = (const float*)d_in[25];
  const float* head_b     = (const float*)d_in[26];

  float* out = (float*)d_out;

  float* ws = (float*)d_ws;
  float* meanp    = ws; ws += 98304;     // (128, 768)
  float* hidden   = ws; ws += 262144;    // (512, 512)
  float* residual = ws; ws += 262144;
  float* xn       = ws; ws += 262144;
  float* xz       = ws; ws += 1048576;   // (512, 2048)
  float* xc       = ws; ws += 524288;    // (512, 1024)
  float* proj     = ws; ws += 32768;     // (512, 64)
  float* dtbuf    = ws; ws += 524288;    // (512, 1024)
  float* yz       = ws; ws += 524288;    // (512, 1024)
  float* labs     = ws; ws += 384;
  float* cpart    = ws; ws += 1048576;   // split-K partials (max 4x512x512)
  float* pmp      = ws; ws += 1376256;   // (1792, 768) patch partials
  u64*   pairs    = (u64*)ws; ws += 524288;  // 2048 x 128 x 8B
  int*   flags    = (int*)ws; ws += 16384;   // 8 layers x 2048 flags

  hipLaunchKernelGGL(patch_part_k, dim3(1792), dim3(192), 0, stream, images, pmp);
  hipLaunchKernelGGL(patch_red_k, dim3(128), dim3(192), 0, stream, pmp, meanp);
  hipLaunchKernelGGL(gemm_bs_k, dim3(8, 2, 8), dim3(256), 0, stream,
                     meanp, patch_w, cpart, 128, 512, 768, 96);
  hipLaunchKernelGGL(tokenize_k, dim3(512), dim3(128), 0, stream, cpart, states, actions,
                     patch_b, state_w, state_b, act_w, act_b, hidden, residual);

  for (int i = 0; i < 8; ++i) {
    const float* n1 = norm1_w + i * 512;
    const float* ipw = in_proj_w + (size_t)i * 2048 * 512;
    const float* cw = conv_w + (size_t)i * 4096;
    const float* cb = conv_b + (size_t)i * 1024;
    const float* xpw = x_proj_w + (size_t)i * 65536;
    const float* dtw = dt_w + (size_t)i * 32768;
    const float* dtbias = dt_b + (size_t)i * 1024;
    const float* al = A_log + (size_t)i * 16384;
    const float* dpp = Dp + (size_t)i * 1024;
    const float* opw = out_proj_w + (size_t)i * 524288;
    const float* n2 = norm2_w + i * 512;
    const float* f1 = fc1_w + (size_t)i * 1048576;
    const float* f2 = fc2_w + (size_t)i * 524288;

    if (i == 0)
      hipLaunchKernelGGL(addnorm_k, dim3(512), dim3(128), 0, stream,
                         hidden, 1, residual, n1, xn);
    else
      hipLaunchKernelGGL(addnorm_k, dim3(512), dim3(128), 0, stream,
                         cpart, 4, residual, n1, xn);
    hipLaunchKernelGGL(gemm_bs_k, dim3(32, 8, 1), dim3(256), 0, stream,
                       xn, ipw, xz, 512, 2048, 512, 512);
    hipLaunchKernelGGL(convproj_k, dim3(512), dim3(256), 0, stream,
                       xz, cw, cb, xpw, dtw, dtbias, xc, proj, dtbuf);
    hipLaunchKernelGGL(scan_k, dim3(2048), dim3(128), 0, stream,
                       dtbuf, proj, xc, xz, al, dpp, pairs, flags + i * 2048, yz);
    hipLaunchKernelGGL(gemm_bs_k, dim3(8, 8, 4), dim3(256), 0, stream,
                       yz, opw, cpart, 512, 512, 1024, 256);
    hipLaunchKernelGGL(addnorm_k, dim3(512), dim3(128), 0, stream,
                       cpart, 4, residual, n2, xn);
    hipLaunchKernelGGL(gemm_bs_k, dim3(32, 8, 1), dim3(256), 0, stream,
                       xn, f1, xz, 512, 2048, 512, 512);
    hipLaunchKernelGGL(gemm_glu_k, dim3(8, 8, 4), dim3(256), 0, stream,
                       xz, f2, cpart, 512, 512, 1024, 256);
  }

  hipLaunchKernelGGL(addnorm_k, dim3(512), dim3(128), 0, stream,
                     cpart, 4, residual, norm_f_w, xn);
  hipLaunchKernelGGL(head_k, dim3(384), dim3(64), 0, stream, xn, head_w, head_b, labels,
                     out + 1, labs);
  hipLaunchKernelGGL(loss_k, dim3(1), dim3(128), 0, stream, labs, seq_length, out);
}

// Round 6
// 1174.777 us; speedup vs baseline: 3.7347x; 3.7347x over previous
//
#include <hip/hip_runtime.h>

// ---------------------------------------------------------------------------
// DVGMamba forward. Round 6: round-5 fusions + round-4 two-pass chunked scan
// (agent-scope flag chaining was a 3.6x regression -- cross-XCD coherence).
// b=2, l=64, S=256 tokens, D=512, DIN=1024, DS=16, DTR=32, K=4, Layers=8
// ---------------------------------------------------------------------------

#define NTOK 512
#define SEQ  256
#define CS   32     // scan chunk size
#define NC   8      // chunks

typedef __attribute__((ext_vector_type(8))) short bf16x8;
typedef __attribute__((ext_vector_type(16))) float f32x16;

__device__ __forceinline__ float silu_f(float x) { return x / (1.0f + expf(-x)); }
__device__ __forceinline__ float softplus_f(float x) {
  return (x > 20.0f) ? x : log1pf(expf(x));
}

// split fp32 -> (hi bf16, lo bf16) by truncation; packed 2x bf16 per dword
__device__ __forceinline__ void split_pack(float4 v, uint2* hi, uint2* lo) {
  uint ux = __float_as_uint(v.x), uy = __float_as_uint(v.y);
  uint uz = __float_as_uint(v.z), uw = __float_as_uint(v.w);
  hi->x = (ux >> 16) | (uy & 0xffff0000u);
  hi->y = (uz >> 16) | (uw & 0xffff0000u);
  float lx = v.x - __uint_as_float(ux & 0xffff0000u);
  float ly = v.y - __uint_as_float(uy & 0xffff0000u);
  float lz = v.z - __uint_as_float(uz & 0xffff0000u);
  float lw = v.w - __uint_as_float(uw & 0xffff0000u);
  lo->x = (__float_as_uint(lx) >> 16) | (__float_as_uint(ly) & 0xffff0000u);
  lo->y = (__float_as_uint(lz) >> 16) | (__float_as_uint(lw) & 0xffff0000u);
}

// --------------------------- split-bf16 MFMA NT GEMM -----------------------
__global__ __launch_bounds__(256) void gemm_bs_k(const float* __restrict__ A,
                                                 const float* __restrict__ B,
                                                 float* __restrict__ C,
                                                 int M, int N, int K, int Kc) {
  __shared__ alignas(16) ushort sAh[2][2][512];
  __shared__ alignas(16) ushort sAl[2][2][512];
  __shared__ alignas(16) ushort sBh[2][2][512];
  __shared__ alignas(16) ushort sBl[2][2][512];
  int t = threadIdx.x;
  int bn = blockIdx.x, bm = blockIdx.y, z = blockIdx.z;
  const float* Ab = A + (size_t)bm * 64 * K + (size_t)z * Kc;
  const float* Bb = B + (size_t)bn * 64 * K + (size_t)z * Kc;
  float* Cb = C + (size_t)z * M * N;
  int r = t >> 2, kc = (t & 3) << 2;
  int st = r >> 5, m = r & 31;
  int off = ((kc >> 3) << 8) + (m << 3) + (kc & 7);
  int w = t >> 6, lane = t & 63;
  int wr = w >> 1, wc = w & 1;

  f32x16 acc;
#pragma unroll
  for (int i = 0; i < 16; ++i) acc[i] = 0.f;

  int nk = Kc >> 4;
  float4 a4 = *(const float4*)&Ab[(size_t)r * K + kc];
  float4 b4 = *(const float4*)&Bb[(size_t)r * K + kc];
  {
    uint2 hi, lo;
    split_pack(a4, &hi, &lo);
    *(uint2*)&sAh[0][st][off] = hi; *(uint2*)&sAl[0][st][off] = lo;
    split_pack(b4, &hi, &lo);
    *(uint2*)&sBh[0][st][off] = hi; *(uint2*)&sBl[0][st][off] = lo;
  }
  __syncthreads();
  for (int ks = 0; ks < nk; ++ks) {
    int buf = ks & 1;
    if (ks + 1 < nk) {
      a4 = *(const float4*)&Ab[(size_t)r * K + (ks + 1) * 16 + kc];
      b4 = *(const float4*)&Bb[(size_t)r * K + (ks + 1) * 16 + kc];
    }
    bf16x8 ah = *(bf16x8*)&sAh[buf][wr][lane << 3];
    bf16x8 al = *(bf16x8*)&sAl[buf][wr][lane << 3];
    bf16x8 bh = *(bf16x8*)&sBh[buf][wc][lane << 3];
    bf16x8 bl = *(bf16x8*)&sBl[buf][wc][lane << 3];
    acc = __builtin_amdgcn_mfma_f32_32x32x16_bf16(ah, bh, acc, 0, 0, 0);
    acc = __builtin_amdgcn_mfma_f32_32x32x16_bf16(al, bh, acc, 0, 0, 0);
    acc = __builtin_amdgcn_mfma_f32_32x32x16_bf16(ah, bl, acc, 0, 0, 0);
    if (ks + 1 < nk) {
      uint2 hi, lo;
      split_pack(a4, &hi, &lo);
      *(uint2*)&sAh[buf ^ 1][st][off] = hi; *(uint2*)&sAl[buf ^ 1][st][off] = lo;
      split_pack(b4, &hi, &lo);
      *(uint2*)&sBh[buf ^ 1][st][off] = hi; *(uint2*)&sBl[buf ^ 1][st][off] = lo;
    }
    __syncthreads();
  }
  int col = lane & 31, rq = lane >> 5;
  float* Cw = Cb + (size_t)(bm * 64 + wr * 32) * N + bn * 64 + wc * 32 + col;
#pragma unroll
  for (int rg = 0; rg < 16; ++rg) {
    int row = (rg & 3) + ((rg >> 2) << 3) + (rq << 2);
    Cw[(size_t)row * N] = acc[rg];
  }
}

// --------------------------- GEMM with fused GLU on A ----------------------
// A_logical[r,k] = g[r*2048+k] * silu(g[r*2048+1024+k]); K = 1024.
__global__ __launch_bounds__(256) void gemm_glu_k(const float* __restrict__ G,
                                                  const float* __restrict__ B,
                                                  float* __restrict__ C,
                                                  int M, int N, int K, int Kc) {
  __shared__ alignas(16) ushort sAh[2][2][512];
  __shared__ alignas(16) ushort sAl[2][2][512];
  __shared__ alignas(16) ushort sBh[2][2][512];
  __shared__ alignas(16) ushort sBl[2][2][512];
  int t = threadIdx.x;
  int bn = blockIdx.x, bm = blockIdx.y, z = blockIdx.z;
  const float* Gb = G + (size_t)bm * 64 * 2048 + (size_t)z * Kc;
  const float* Bb = B + (size_t)bn * 64 * K + (size_t)z * Kc;
  float* Cb = C + (size_t)z * M * N;
  int r = t >> 2, kc = (t & 3) << 2;
  int st = r >> 5, m = r & 31;
  int off = ((kc >> 3) << 8) + (m << 3) + (kc & 7);
  int w = t >> 6, lane = t & 63;
  int wr = w >> 1, wc = w & 1;

  f32x16 acc;
#pragma unroll
  for (int i = 0; i < 16; ++i) acc[i] = 0.f;

  int nk = Kc >> 4;
  const float* gr = Gb + (size_t)r * 2048 + kc;
  float4 ga = *(const float4*)&gr[0];
  float4 gz = *(const float4*)&gr[1024];
  float4 b4 = *(const float4*)&Bb[(size_t)r * K + kc];
  {
    float4 a4 = {ga.x * silu_f(gz.x), ga.y * silu_f(gz.y),
                 ga.z * silu_f(gz.z), ga.w * silu_f(gz.w)};
    uint2 hi, lo;
    split_pack(a4, &hi, &lo);
    *(uint2*)&sAh[0][st][off] = hi; *(uint2*)&sAl[0][st][off] = lo;
    split_pack(b4, &hi, &lo);
    *(uint2*)&sBh[0][st][off] = hi; *(uint2*)&sBl[0][st][off] = lo;
  }
  __syncthreads();
  for (int ks = 0; ks < nk; ++ks) {
    int buf = ks & 1;
    if (ks + 1 < nk) {
      ga = *(const float4*)&gr[(ks + 1) * 16];
      gz = *(const float4*)&gr[1024 + (ks + 1) * 16];
      b4 = *(const float4*)&Bb[(size_t)r * K + (ks + 1) * 16 + kc];
    }
    bf16x8 ah = *(bf16x8*)&sAh[buf][wr][lane << 3];
    bf16x8 al = *(bf16x8*)&sAl[buf][wr][lane << 3];
    bf16x8 bh = *(bf16x8*)&sBh[buf][wc][lane << 3];
    bf16x8 bl = *(bf16x8*)&sBl[buf][wc][lane << 3];
    acc = __builtin_amdgcn_mfma_f32_32x32x16_bf16(ah, bh, acc, 0, 0, 0);
    acc = __builtin_amdgcn_mfma_f32_32x32x16_bf16(al, bh, acc, 0, 0, 0);
    acc = __builtin_amdgcn_mfma_f32_32x32x16_bf16(ah, bl, acc, 0, 0, 0);
    if (ks + 1 < nk) {
      float4 a4 = {ga.x * silu_f(gz.x), ga.y * silu_f(gz.y),
                   ga.z * silu_f(gz.z), ga.w * silu_f(gz.w)};
      uint2 hi, lo;
      split_pack(a4, &hi, &lo);
      *(uint2*)&sAh[buf ^ 1][st][off] = hi; *(uint2*)&sAl[buf ^ 1][st][off] = lo;
      split_pack(b4, &hi, &lo);
      *(uint2*)&sBh[buf ^ 1][st][off] = hi; *(uint2*)&sBl[buf ^ 1][st][off] = lo;
    }
    __syncthreads();
  }
  int col = lane & 31, rq = lane >> 5;
  float* Cw = Cb + (size_t)(bm * 64 + wr * 32) * N + bn * 64 + wc * 32 + col;
#pragma unroll
  for (int rg = 0; rg < 16; ++rg) {
    int row = (rg & 3) + ((rg >> 2) << 3) + (rq << 2);
    Cw[(size_t)row * N] = acc[rg];
  }
}

// --------------------------- patch mean, two stage -------------------------
__global__ void patch_part_k(const float* __restrict__ img, float* __restrict__ pmp) {
  int blk = blockIdx.x;
  int bl = blk / 14, hb = blk % 14;
  int t = threadIdx.x;                 // = c*64 + hi*4 + wi4
  int c = t >> 6, hi = (t >> 2) & 15, wi4 = t & 3;
  const float* base = img + (size_t)bl * 3 * 50176 + (size_t)c * 50176 +
                      (size_t)(hb * 16 + hi) * 224 + wi4 * 4;
  float4 s = {0.f, 0.f, 0.f, 0.f};
#pragma unroll
  for (int wb = 0; wb < 14; ++wb) {
    float4 v = *(const float4*)&base[wb * 16];
    s.x += v.x; s.y += v.y; s.z += v.z; s.w += v.w;
  }
  ((float4*)(pmp + (size_t)blk * 768))[t] = s;
}

__global__ void patch_red_k(const float* __restrict__ pmp, float* __restrict__ meanp) {
  int bl = blockIdx.x;
  int t = threadIdx.x;
  float4 s = {0.f, 0.f, 0.f, 0.f};
  for (int hb = 0; hb < 14; ++hb) {
    float4 v = ((const float4*)(pmp + (size_t)(bl * 14 + hb) * 768))[t];
    s.x += v.x; s.y += v.y; s.z += v.z; s.w += v.w;
  }
  const float inv = 1.0f / 196.0f;
  float4 o = {s.x * inv, s.y * inv, s.z * inv, s.w * inv};
  ((float4*)(meanp + (size_t)bl * 768))[t] = o;
}

// --------------------------- tokenize (scatter) ----------------------------
__global__ void tokenize_k(const float* __restrict__ imgp,
                           const float* __restrict__ states,
                           const float* __restrict__ actions,
                           const float* __restrict__ pb,
                           const float* __restrict__ sw, const float* __restrict__ sb,
                           const float* __restrict__ aw, const float* __restrict__ ab,
                           float* __restrict__ hidden, float* __restrict__ residual) {
  int tok = blockIdx.x;
  int t = threadIdx.x;
  int j = tok & 3;
  int bl = tok >> 2;
  int o0 = t * 4;
  float out[4];
  if (j == 0) {
    float4 a = ((const float4*)pb)[t];
    const float* ip = imgp + (size_t)bl * 512;
#pragma unroll
    for (int p = 0; p < 8; ++p) {
      float4 v = ((const float4*)(ip + (size_t)p * 65536))[t];
      a.x += v.x; a.y += v.y; a.z += v.z; a.w += v.w;
    }
    out[0] = a.x; out[1] = a.y; out[2] = a.z; out[3] = a.w;
  } else if (j == 1) {
    const float* sv = states + (size_t)bl * 21;
#pragma unroll
    for (int i = 0; i < 4; ++i) {
      int o = o0 + i;
      float acc = sb[o];
      for (int k = 0; k < 7; ++k) acc += sw[o * 7 + k] * sv[k];
      out[i] = acc;
    }
  } else {
    const float* av = actions + ((size_t)bl * 3 + (j - 2)) * 4;
#pragma unroll
    for (int i = 0; i < 4; ++i) {
      int o = o0 + i;
      float acc = ab[o];
      for (int k = 0; k < 4; ++k) acc += aw[o * 4 + k] * av[k];
      out[i] = acc;
    }
  }
  float4 ov = {out[0], out[1], out[2], out[3]};
  ((float4*)(hidden + (size_t)tok * 512))[t] = ov;
  float4 z4 = {0.f, 0.f, 0.f, 0.f};
  ((float4*)(residual + (size_t)tok * 512))[t] = z4;
}

// --------------------------- add + rmsnorm ---------------------------------
__global__ void addnorm_k(const float* __restrict__ hid, int parts,
                          float* __restrict__ res,
                          const float* __restrict__ w, float* __restrict__ xn) {
  int tok = blockIdx.x;
  int t = threadIdx.x;
  float4* r4 = (float4*)(res + (size_t)tok * 512);
  float4 r = r4[t];
  const float4* hp = (const float4*)(hid + (size_t)tok * 512);
  for (int p = 0; p < parts; ++p) {
    float4 h = hp[t];
    r.x += h.x; r.y += h.y; r.z += h.z; r.w += h.w;
    hp += 65536;                       // 512*512 floats between parts
  }
  r4[t] = r;
  float ss = r.x * r.x + r.y * r.y + r.z * r.z + r.w * r.w;
  for (int off = 32; off; off >>= 1) ss += __shfl_down(ss, off, 64);
  __shared__ float s2[2];
  if ((t & 63) == 0) s2[t >> 6] = ss;
  __syncthreads();
  float tot = s2[0] + s2[1];
  float scale = rsqrtf(tot * (1.0f / 512.0f) + 1e-5f);
  float4 wv = ((const float4*)w)[t];
  float4 o = {r.x * scale * wv.x, r.y * scale * wv.y,
              r.z * scale * wv.z, r.w * scale * wv.w};
  ((float4*)(xn + (size_t)tok * 512))[t] = o;
}

// --------------------------- fused conv+silu+xproj+dt ----------------------
__global__ __launch_bounds__(256) void convproj_k(const float* __restrict__ xz,
                                                  const float* __restrict__ cw,
                                                  const float* __restrict__ cb,
                                                  const float* __restrict__ xpw,
                                                  const float* __restrict__ dtw,
                                                  const float* __restrict__ dtbias,
                                                  float* __restrict__ xc,
                                                  float* __restrict__ proj,
                                                  float* __restrict__ dt) {
  int tok = blockIdx.x;
  int t = threadIdx.x;
  int b = tok >> 8, s = tok & 255;
  __shared__ float xr[1024];
  __shared__ float pp[4][64];
  __shared__ float pr[64];
  int d4 = t * 4;
  float4 cw0 = ((const float4*)cw)[d4];
  float4 cw1 = ((const float4*)cw)[d4 + 1];
  float4 cw2 = ((const float4*)cw)[d4 + 2];
  float4 cw3 = ((const float4*)cw)[d4 + 3];
  float acc0 = cb[d4], acc1 = cb[d4 + 1], acc2 = cb[d4 + 2], acc3 = cb[d4 + 3];
  const float* base = xz + (size_t)b * 256 * 2048 + d4;
  const float wk0[4] = {cw0.x, cw0.y, cw0.z, cw0.w};
  const float wk1[4] = {cw1.x, cw1.y, cw1.z, cw1.w};
  const float wk2[4] = {cw2.x, cw2.y, cw2.z, cw2.w};
  const float wk3[4] = {cw3.x, cw3.y, cw3.z, cw3.w};
#pragma unroll
  for (int k = 0; k < 4; ++k) {
    int row = s + k - 3;
    if (row >= 0) {
      float4 v = *(const float4*)&base[(size_t)row * 2048];
      acc0 += wk0[k] * v.x; acc1 += wk1[k] * v.y;
      acc2 += wk2[k] * v.z; acc3 += wk3[k] * v.w;
    }
  }
  float4 xc4 = {silu_f(acc0), silu_f(acc1), silu_f(acc2), silu_f(acc3)};
  ((float4*)(xc + (size_t)tok * 1024))[t] = xc4;
  *(float4*)&xr[d4] = xc4;
  __syncthreads();
  int n = t & 63, q = t >> 6;
  {
    const float* wrow = xpw + (size_t)n * 1024 + q * 256;
    const float* xq = xr + q * 256;
    float acc = 0.f;
    for (int k = 0; k < 256; k += 4)
      acc += wrow[k] * xq[k] + wrow[k + 1] * xq[k + 1] +
             wrow[k + 2] * xq[k + 2] + wrow[k + 3] * xq[k + 3];
    pp[q][n] = acc;
  }
  __syncthreads();
  if (t < 64) {
    float v = pp[0][t] + pp[1][t] + pp[2][t] + pp[3][t];
    pr[t] = v;
    proj[(size_t)tok * 64 + t] = v;
  }
  __syncthreads();
#pragma unroll
  for (int i = 0; i < 4; ++i) {
    int d = t * 4 + i;
    const float* dw = dtw + (size_t)d * 32;
    float a = dtbias[d];
    for (int k = 0; k < 32; ++k) a += dw[k] * pr[k];
    dt[(size_t)tok * 1024 + d] = softplus_f(a);
  }
}

// --------------------------- scan pass 1: chunk pairs ----------------------
// grid (256, 8): x = b*128+dgroup, y = chunk. 128 thr = 8 d x 16 n.
__global__ __launch_bounds__(128) void scan1_k(const float* __restrict__ dt,
                                               const float* __restrict__ proj,
                                               const float* __restrict__ xc,
                                               const float* __restrict__ alog,
                                               float2* __restrict__ pairs) {
  __shared__ float sDt[CS][8];
  __shared__ float sXc[CS][8];
  __shared__ float sB[CS][16];
  int t = threadIdx.x;
  int g = blockIdx.x, c = blockIdx.y;
  int b = g >> 7;
  int d0 = (g & 127) << 3;
  int dl = t >> 4, n = t & 15;
  int d = d0 + dl;
  int s0 = c * CS;
  float A = -expf(alog[d * 16 + n]);
  const float* dtb = dt + ((size_t)b * SEQ + s0) * 1024 + d0;
  const float* xcb = xc + ((size_t)b * SEQ + s0) * 1024 + d0;
  const float* pbp = proj + ((size_t)b * SEQ + s0) * 64 + 32;
  if (t < 64) {
    int li = t >> 1, lc4 = (t & 1) * 4;
    *(float4*)&sDt[li][lc4] = *(const float4*)&dtb[(size_t)li * 1024 + lc4];
    *(float4*)&sXc[li][lc4] = *(const float4*)&xcb[(size_t)li * 1024 + lc4];
  }
  {
    int r = t >> 2, c4 = (t & 3) * 4;
    *(float4*)&sB[r][c4] = *(const float4*)&pbp[(size_t)r * 64 + c4];
  }
  __syncthreads();
  float Ap = 1.f, Bacc = 0.f;
#pragma unroll
  for (int i = 0; i < CS; ++i) {
    float dtv = sDt[i][dl];
    float dA = __expf(dtv * A);
    Bacc = dA * Bacc + dtv * sB[i][n] * sXc[i][dl];
    Ap *= dA;
  }
  pairs[(((size_t)c * 2 + b) * 1024 + d) * 16 + n] = make_float2(Ap, Bacc);
}

// --------------------------- scan pass 2: apply + gate ---------------------
__global__ __launch_bounds__(128) void scan2_k(const float* __restrict__ dt,
                                               const float* __restrict__ proj,
                                               const float* __restrict__ xc,
                                               const float* __restrict__ xz,
                                               const float* __restrict__ alog,
                                               const float* __restrict__ Dp,
                                               const float2* __restrict__ pairs,
                                               float* __restrict__ yz) {
  __shared__ float sDt[CS][8];
  __shared__ float sXc[CS][8];
  __shared__ float sZ[CS][8];
  __shared__ float sBC[CS][32];
  __shared__ float sY[CS][8];
  int t = threadIdx.x;
  int g = blockIdx.x, c = blockIdx.y;
  int b = g >> 7;
  int d0 = (g & 127) << 3;
  int dl = t >> 4, n = t & 15;
  int d = d0 + dl;
  int s0 = c * CS;
  float A = -expf(alog[d * 16 + n]);
  float dp = Dp[d];
  const float* dtb = dt + ((size_t)b * SEQ + s0) * 1024 + d0;
  const float* xcb = xc + ((size_t)b * SEQ + s0) * 1024 + d0;
  const float* zb  = xz + ((size_t)b * SEQ + s0) * 2048 + 1024 + d0;
  const float* pbp = proj + ((size_t)b * SEQ + s0) * 64 + 32;
  float* yb = yz + ((size_t)b * SEQ + s0) * 1024 + d0;
  float h = 0.f;
  for (int cc = 0; cc < c; ++cc) {
    float2 p = pairs[(((size_t)cc * 2 + b) * 1024 + d) * 16 + n];
    h = p.x * h + p.y;
  }
  bool lowh = t < 64;
  int u = lowh ? t : t - 64;
  int li = u >> 1, lc4 = (u & 1) * 4;
  if (lowh) {
    *(float4*)&sDt[li][lc4] = *(const float4*)&dtb[(size_t)li * 1024 + lc4];
    *(float4*)&sXc[li][lc4] = *(const float4*)&xcb[(size_t)li * 1024 + lc4];
  } else {
    *(float4*)&sZ[li][lc4] = *(const float4*)&zb[(size_t)li * 2048 + lc4];
  }
  {
    int v0i = t >> 3, v0c = (t & 7) * 4;
    int v1i = (t + 128) >> 3, v1c = ((t + 128) & 7) * 4;
    *(float4*)&sBC[v0i][v0c] = *(const float4*)&pbp[(size_t)v0i * 64 + v0c];
    *(float4*)&sBC[v1i][v1c] = *(const float4*)&pbp[(size_t)v1i * 64 + v1c];
  }
  __syncthreads();
#pragma unroll
  for (int i = 0; i < CS; ++i) {
    float dtv = sDt[i][dl];
    float xcv = sXc[i][dl];
    float dA = __expf(dtv * A);
    h = dA * h + dtv * sBC[i][n] * xcv;
    float yc = h * sBC[i][16 + n];
    yc += __shfl_xor(yc, 1, 64);
    yc += __shfl_xor(yc, 2, 64);
    yc += __shfl_xor(yc, 4, 64);
    yc += __shfl_xor(yc, 8, 64);
    if (n == 0) sY[i][dl] = (yc + dp * xcv) * silu_f(sZ[i][dl]);
  }
  __syncthreads();
  if (lowh)
    *(float4*)&yb[(size_t)li * 1024 + lc4] = *(const float4*)&sY[li][lc4];
}

// --------------------------- head + |diff| ---------------------------------
__global__ void head_k(const float* __restrict__ hf, const float* __restrict__ hw,
                       const float* __restrict__ hb, const float* __restrict__ labels,
                       float* __restrict__ preds, float* __restrict__ labs) {
  int blk = blockIdx.x;
  int j = blk % 3;
  int l = (blk / 3) % 64;
  int b = blk / 192;
  int row = b * 256 + l * 4 + 1 + j;
  int t = threadIdx.x;
  const float* x = hf + (size_t)row * 512;
  float acc[4] = {0.f, 0.f, 0.f, 0.f};
  for (int k = t; k < 512; k += 64) {
    float xv = x[k];
#pragma unroll
    for (int a = 0; a < 4; ++a) acc[a] += xv * hw[a * 512 + k];
  }
  for (int off = 32; off; off >>= 1) {
#pragma unroll
    for (int a = 0; a < 4; ++a) acc[a] += __shfl_down(acc[a], off, 64);
  }
  if (t == 0) {
    const float* lab = labels + (size_t)blk * 4;
    float sd = 0.f;
#pragma unroll
    for (int a = 0; a < 4; ++a) {
      float p = acc[a] + hb[a];
      preds[(size_t)blk * 4 + a] = p;
      sd += fabsf(p - lab[a]);
    }
    labs[blk] = sd;
  }
}

// --------------------------- loss ------------------------------------------
__global__ void loss_k(const float* __restrict__ labs, const int* __restrict__ seqlen,
                       float* __restrict__ out) {
  int t = threadIdx.x;
  int b = t >> 6, l = t & 63;
  float la = (labs[(b * 64 + l) * 3] + labs[(b * 64 + l) * 3 + 1] +
              labs[(b * 64 + l) * 3 + 2]) * (1.0f / 12.0f);
  float m = (l < seqlen[b]) ? 1.f : 0.f;
  float v = la * m;
  for (int off = 32; off; off >>= 1) {
    v += __shfl_down(v, off, 64);
    m += __shfl_down(m, off, 64);
  }
  __shared__ float sb_[2];
  if ((t & 63) == 0) sb_[b] = v / fmaxf(m, 1.0f);
  __syncthreads();
  if (t == 0) out[0] = 0.5f * (sb_[0] + sb_[1]);
}

// ---------------------------------------------------------------------------
extern "C" void kernel_launch(void* const* d_in, const int* in_sizes, int n_in,
                              void* d_out, int out_size, void* d_ws, size_t ws_size,
                              hipStream_t stream) {
  const float* images     = (const float*)d_in[0];
  const int*   seq_length = (const int*)d_in[1];
  const float* states     = (const float*)d_in[2];
  const float* actions    = (const float*)d_in[3];
  const float* labels     = (const float*)d_in[4];
  const float* patch_w    = (const float*)d_in[5];
  const float* patch_b    = (const float*)d_in[6];
  const float* state_w    = (const float*)d_in[7];
  const float* state_b    = (const float*)d_in[8];
  const float* act_w      = (const float*)d_in[9];
  const float* act_b      = (const float*)d_in[10];
  const float* norm1_w    = (const float*)d_in[11];
  const float* in_proj_w  = (const float*)d_in[12];
  const float* conv_w     = (const float*)d_in[13];
  const float* conv_b     = (const float*)d_in[14];
  const float* x_proj_w   = (const float*)d_in[15];
  const float* dt_w       = (const float*)d_in[16];
  const float* dt_b       = (const float*)d_in[17];
  const float* A_log      = (const float*)d_in[18];
  const float* Dp         = (const float*)d_in[19];
  const float* out_proj_w = (const float*)d_in[20];
  const float* norm2_w    = (const float*)d_in[21];
  const float* fc1_w      = (const float*)d_in[22];
  const float* fc2_w      = (const float*)d_in[23];
  const float* norm_f_w   = (const float*)d_in[24];
  const float* head_w     = (const float*)d_in[25];
  const float* head_b     = (const float*)d_in[26];

  float* out = (float*)d_out;

  float* ws = (float*)d_ws;
  float* meanp    = ws; ws += 98304;     // (128, 768)
  float* hidden   = ws; ws += 262144;    // (512, 512)
  float* residual = ws; ws += 262144;
  float* xn       = ws; ws += 262144;
  float* xz       = ws; ws += 1048576;   // (512, 2048)
  float* xc       = ws; ws += 524288;    // (512, 1024)
  float* proj     = ws; ws += 32768;     // (512, 64)
  float* dtbuf    = ws; ws += 524288;    // (512, 1024)
  float* yz       = ws; ws += 524288;    // (512, 1024)
  float* labs     = ws; ws += 384;
  float* cpart    = ws; ws += 1048576;   // split-K partials (max 4x512x512)
  float* pmp      = ws; ws += 1376256;   // (1792, 768) patch partials
  float2* pairs   = (float2*)ws; ws += 524288;  // (8,2,1024,16) float2

  hipLaunchKernelGGL(patch_part_k, dim3(1792), dim3(192), 0, stream, images, pmp);
  hipLaunchKernelGGL(patch_red_k, dim3(128), dim3(192), 0, stream, pmp, meanp);
  hipLaunchKernelGGL(gemm_bs_k, dim3(8, 2, 8), dim3(256), 0, stream,
                     meanp, patch_w, cpart, 128, 512, 768, 96);
  hipLaunchKernelGGL(tokenize_k, dim3(512), dim3(128), 0, stream, cpart, states, actions,
                     patch_b, state_w, state_b, act_w, act_b, hidden, residual);

  for (int i = 0; i < 8; ++i) {
    const float* n1 = norm1_w + i * 512;
    const float* ipw = in_proj_w + (size_t)i * 2048 * 512;
    const float* cw = conv_w + (size_t)i * 4096;
    const float* cb = conv_b + (size_t)i * 1024;
    const float* xpw = x_proj_w + (size_t)i * 65536;
    const float* dtw = dt_w + (size_t)i * 32768;
    const float* dtbias = dt_b + (size_t)i * 1024;
    const float* al = A_log + (size_t)i * 16384;
    const float* dpp = Dp + (size_t)i * 1024;
    const float* opw = out_proj_w + (size_t)i * 524288;
    const float* n2 = norm2_w + i * 512;
    const float* f1 = fc1_w + (size_t)i * 1048576;
    const float* f2 = fc2_w + (size_t)i * 524288;

    if (i == 0)
      hipLaunchKernelGGL(addnorm_k, dim3(512), dim3(128), 0, stream,
                         hidden, 1, residual, n1, xn);
    else
      hipLaunchKernelGGL(addnorm_k, dim3(512), dim3(128), 0, stream,
                         cpart, 4, residual, n1, xn);
    hipLaunchKernelGGL(gemm_bs_k, dim3(32, 8, 1), dim3(256), 0, stream,
                       xn, ipw, xz, 512, 2048, 512, 512);
    hipLaunchKernelGGL(convproj_k, dim3(512), dim3(256), 0, stream,
                       xz, cw, cb, xpw, dtw, dtbias, xc, proj, dtbuf);
    hipLaunchKernelGGL(scan1_k, dim3(256, 8), dim3(128), 0, stream,
                       dtbuf, proj, xc, al, pairs);
    hipLaunchKernelGGL(scan2_k, dim3(256, 8), dim3(128), 0, stream,
                       dtbuf, proj, xc, xz, al, dpp, pairs, yz);
    hipLaunchKernelGGL(gemm_bs_k, dim3(8, 8, 4), dim3(256), 0, stream,
                       yz, opw, cpart, 512, 512, 1024, 256);
    hipLaunchKernelGGL(addnorm_k, dim3(512), dim3(128), 0, stream,
                       cpart, 4, residual, n2, xn);
    hipLaunchKernelGGL(gemm_bs_k, dim3(32, 8, 1), dim3(256), 0, stream,
                       xn, f1, xz, 512, 2048, 512, 512);
    hipLaunchKernelGGL(gemm_glu_k, dim3(8, 8, 4), dim3(256), 0, stream,
                       xz, f2, cpart, 512, 512, 1024, 256);
  }

  hipLaunchKernelGGL(addnorm_k, dim3(512), dim3(128), 0, stream,
                     cpart, 4, residual, norm_f_w, xn);
  hipLaunchKernelGGL(head_k, dim3(384), dim3(64), 0, stream, xn, head_w, head_b, labels,
                     out + 1, labs);
  hipLaunchKernelGGL(loss_k, dim3(1), dim3(128), 0, stream, labs, seq_length, out);
}